// Round 1
// baseline (257.856 us; speedup 1.0000x reference)
//
#include <hip/hip_runtime.h>
#include <hip/hip_bf16.h>

// Problem constants
#define B_ROWS 4096
#define NN     8192
#define DD     128
#define CSPLIT 8            // column splits (blocks per row-group)
#define NSPLIT (CSPLIT * 2) // wn adds another factor of 2

typedef __attribute__((ext_vector_type(8))) short s8v;   // 8 bf16 (4 VGPR)
typedef __attribute__((ext_vector_type(4))) float f4v;   // 4 f32
typedef __attribute__((ext_vector_type(2))) float f2v;

static constexpr float SCALE_H = 1.6986436f;      // sqrt(2*log2(e)); s^2 folds /TEMP and log2e into the matmul
static constexpr float SCALE2  = 2.8853900818f;   // 2*log2(e)
static constexpr float LN2     = 0.6931471805599453f;
static constexpr float MASKVAL = -3.0e38f;
static constexpr float MINIT   = -1.0e30f;

// ---- kernel 1: f32 -> scaled bf16 concat(h_i, h_j) ----
__global__ void prep_kernel(const float* __restrict__ hi, const float* __restrict__ hj,
                            __hip_bfloat16* __restrict__ hb) {
    int t = blockIdx.x * 256 + threadIdx.x;     // 131072 threads, 8 elems each
    int base = t * 8;
    const float* src = (base < B_ROWS * DD) ? (hi + base) : (hj + (base - B_ROWS * DD));
    f4v a = ((const f4v*)src)[0];
    f4v b = ((const f4v*)src)[1];
    union { s8v v; __hip_bfloat16 h[8]; } u;
    u.h[0] = __float2bfloat16(a[0] * SCALE_H);
    u.h[1] = __float2bfloat16(a[1] * SCALE_H);
    u.h[2] = __float2bfloat16(a[2] * SCALE_H);
    u.h[3] = __float2bfloat16(a[3] * SCALE_H);
    u.h[4] = __float2bfloat16(b[0] * SCALE_H);
    u.h[5] = __float2bfloat16(b[1] * SCALE_H);
    u.h[6] = __float2bfloat16(b[2] * SCALE_H);
    u.h[7] = __float2bfloat16(b[3] * SCALE_H);
    ((s8v*)hb)[t] = u.v;
}

// ---- kernel 2: pos2[i] = 2*log2e * dot_f32(h_i[i], h_j[i]) ----
__global__ void pos_kernel(const float* __restrict__ hi, const float* __restrict__ hj,
                           float* __restrict__ pos2) {
    int w = threadIdx.x >> 6, l = threadIdx.x & 63;
    int row = blockIdx.x * 4 + w;
    f2v a = ((const f2v*)(hi + (size_t)row * DD))[l];
    f2v b = ((const f2v*)(hj + (size_t)row * DD))[l];
    float d = a[0] * b[0] + a[1] * b[1];
    #pragma unroll
    for (int off = 32; off; off >>= 1) d += __shfl_xor(d, off, 64);
    if (l == 0) pos2[row] = SCALE2 * d;
}

// ---- kernel 3: fused sim*S2 + masked online logsumexp (log2 domain) ----
// Block: 256 thr = 4 waves. Wave (wm,wn). Rows: {r0..r0+15} U {+B} (fm picks half).
// Cols per step: {pc0..pc0+31} U {+B} (fn&1 picks 16-col subtile, fn>>1 picks +B half).
// One S load feeds 4 sim elements (fm x colhalf).
__global__ __launch_bounds__(256, 3)
void main_kernel(const __hip_bfloat16* __restrict__ hb, const float* __restrict__ S,
                 float* __restrict__ msplit, float* __restrict__ ssplit) {
    const int tid = threadIdx.x;
    const int l  = tid & 63;
    const int w  = tid >> 6;
    const int wm = w >> 1, wn = w & 1;
    const int rb = blockIdx.x & 127;
    const int cs = blockIdx.x >> 7;
    const int r0 = rb * 32 + wm * 16;    // wave row base (first half)
    const int c0 = cs * 512;             // pair-column range for this split
    const int lc = l & 15;               // frag row/col within 16
    const int lk = l >> 4;               // k-group

    const s8v* hb8 = (const s8v*)hb;     // 16 x s8v per row of 128 bf16

    // A fragments, hoisted for the entire sweep: afr[fm][kk]
    s8v afr[2][4];
    #pragma unroll
    for (int fm = 0; fm < 2; fm++) {
        int ar = r0 + lc + fm * B_ROWS;
        #pragma unroll
        for (int kk = 0; kk < 4; kk++)
            afr[fm][kk] = hb8[ar * 16 + kk * 4 + lk];
    }

    float m[2][4], ssum[2][4];
    #pragma unroll
    for (int fm = 0; fm < 2; fm++)
        #pragma unroll
        for (int r = 0; r < 4; r++) { m[fm][r] = MINIT; ssum[fm][r] = 0.f; }

    const int srowbase = r0 + lk * 4;    // S row (== gr & 4095) for (r)

    for (int t = 0; t < 8; t++) {
        const int pc0 = c0 + t * 64 + wn * 32;

        f4v acc[2][4];
        #pragma unroll
        for (int fm = 0; fm < 2; fm++)
            #pragma unroll
            for (int fn = 0; fn < 4; fn++) acc[fm][fn] = f4v{0.f, 0.f, 0.f, 0.f};

        #pragma unroll
        for (int kk = 0; kk < 4; kk++) {
            s8v bfr[4];
            #pragma unroll
            for (int fn = 0; fn < 4; fn++) {
                int bc = pc0 + (fn & 1) * 16 + lc + ((fn >> 1) ? B_ROWS : 0);
                bfr[fn] = hb8[bc * 16 + kk * 4 + lk];
            }
            #pragma unroll
            for (int fm = 0; fm < 2; fm++)
                #pragma unroll
                for (int fn = 0; fn < 4; fn++)
                    acc[fm][fn] = __builtin_amdgcn_mfma_f32_16x16x32_bf16(
                        afr[fm][kk], bfr[fn], acc[fm][fn], 0, 0, 0);
        }

        // epilogue: scale by (1 - S^2), mask, online lse update
        #pragma unroll
        for (int r = 0; r < 4; r++) {
            const int srow = srowbase + r;
            const float* Srow = S + (size_t)srow * B_ROWS;
            #pragma unroll
            for (int fp = 0; fp < 2; fp++) {           // column subtile (fn&1)
                const int scol = pc0 + fp * 16 + lc;
                const float Sv = Srow[scol];
                const float s2 = 1.f - Sv * Sv;
                const bool msk = (scol == srow);       // covers j==n and j==(n+B)%N
                #pragma unroll
                for (int fm = 0; fm < 2; fm++) {
                    #pragma unroll
                    for (int fh = 0; fh < 2; fh++) {   // column +B half (fn>>1)
                        const int fn = fh * 2 + fp;
                        float v1 = msk ? MASKVAL : acc[fm][fn][r] * s2;
                        float nm = fmaxf(m[fm][r], v1);
                        if (nm > m[fm][r]) {           // rare rescale path
                            ssum[fm][r] *= exp2f(m[fm][r] - nm);
                            m[fm][r] = nm;
                        }
                        ssum[fm][r] += exp2f(v1 - nm);
                    }
                }
            }
        }
    }

    // reduce (m,s) across the 16 lanes holding the same row, write per-split state
    #pragma unroll
    for (int fm = 0; fm < 2; fm++) {
        #pragma unroll
        for (int r = 0; r < 4; r++) {
            float mm = m[fm][r], ss = ssum[fm][r];
            #pragma unroll
            for (int off = 1; off < 16; off <<= 1) {
                float mo = __shfl_xor(mm, off, 64);
                float so = __shfl_xor(ss, off, 64);
                float nm = fmaxf(mm, mo);
                ss = ss * exp2f(mm - nm) + so * exp2f(mo - nm);
                mm = nm;
            }
            if (lc == 0) {
                int gr = srowbase + r + fm * B_ROWS;
                int sp = cs * 2 + wn;
                msplit[sp * NN + gr] = mm;
                ssplit[sp * NN + gr] = ss;
            }
        }
    }
}

// ---- kernel 4: merge splits + pos logit, deterministic sum ----
__global__ void final_kernel(const float* __restrict__ msplit, const float* __restrict__ ssplit,
                             const float* __restrict__ pos2, float* __restrict__ out) {
    __shared__ float red[256];
    float local = 0.f;
    for (int n = threadIdx.x; n < NN; n += 256) {
        float p = pos2[n & (B_ROWS - 1)];
        float M = p, Ssum = 1.f;                 // pos logit seeds the lse
        for (int sp = 0; sp < NSPLIT; sp++) {
            float mo = msplit[sp * NN + n];
            float so = ssplit[sp * NN + n];
            float nm = fmaxf(M, mo);
            Ssum = Ssum * exp2f(M - nm) + so * exp2f(mo - nm);
            M = nm;
        }
        local += (M + log2f(Ssum)) - p;          // log2 units
    }
    red[threadIdx.x] = local;
    __syncthreads();
    for (int st = 128; st; st >>= 1) {
        if (threadIdx.x < st) red[threadIdx.x] += red[threadIdx.x + st];
        __syncthreads();
    }
    if (threadIdx.x == 0) out[0] = red[0] * (LN2 / (float)NN);
}

extern "C" void kernel_launch(void* const* d_in, const int* in_sizes, int n_in,
                              void* d_out, int out_size, void* d_ws, size_t ws_size,
                              hipStream_t stream) {
    (void)in_sizes; (void)n_in; (void)out_size; (void)ws_size;
    const float* hi = (const float*)d_in[0];
    const float* hj = (const float*)d_in[1];
    const float* S  = (const float*)d_in[2];

    char* ws = (char*)d_ws;
    __hip_bfloat16* hb = (__hip_bfloat16*)ws;                      // 2 MB
    float* pos2   = (float*)(ws + 2097152);                        // 16 KB
    float* msplit = (float*)(ws + 2097152 + 16384);                // 512 KB
    float* ssplit = (float*)(ws + 2097152 + 16384 + 524288);       // 512 KB

    prep_kernel<<<512, 256, 0, stream>>>(hi, hj, hb);
    pos_kernel<<<1024, 256, 0, stream>>>(hi, hj, pos2);
    main_kernel<<<1024, 256, 0, stream>>>(hb, S, msplit, ssplit);
    final_kernel<<<1, 256, 0, stream>>>(msplit, ssplit, pos2, (float*)d_out);
}

// Round 2
// 113.470 us; speedup vs baseline: 2.2725x; 2.2725x over previous
//
#include <hip/hip_runtime.h>
#include <hip/hip_bf16.h>

// Problem constants
#define B_ROWS 4096
#define NN     8192
#define DD     128
#define CSPLIT 8            // column splits (blocks per row-group)
#define NSPLIT (CSPLIT * 2) // wn adds another factor of 2

typedef __attribute__((ext_vector_type(8))) short s8v;   // 8 bf16 (4 VGPR)
typedef __attribute__((ext_vector_type(4))) float f4v;   // 4 f32
typedef __attribute__((ext_vector_type(2))) float f2v;

static constexpr float SCALE_H = 1.6986436f;      // sqrt(2*log2(e)); s^2 folds /TEMP and log2e into the matmul
static constexpr float SCALE2  = 2.8853900818f;   // 2*log2(e)
static constexpr float LN2     = 0.6931471805599453f;
static constexpr float MASKVAL = -3.0e38f;
static constexpr float MINIT   = -1.0e30f;

// ---- kernel 1: f32 -> scaled bf16 concat(h_i, h_j) ----
__global__ void prep_kernel(const float* __restrict__ hi, const float* __restrict__ hj,
                            __hip_bfloat16* __restrict__ hb) {
    int t = blockIdx.x * 256 + threadIdx.x;     // 131072 threads, 8 elems each
    int base = t * 8;
    const float* src = (base < B_ROWS * DD) ? (hi + base) : (hj + (base - B_ROWS * DD));
    f4v a = ((const f4v*)src)[0];
    f4v b = ((const f4v*)src)[1];
    union { s8v v; __hip_bfloat16 h[8]; } u;
    u.h[0] = __float2bfloat16(a[0] * SCALE_H);
    u.h[1] = __float2bfloat16(a[1] * SCALE_H);
    u.h[2] = __float2bfloat16(a[2] * SCALE_H);
    u.h[3] = __float2bfloat16(a[3] * SCALE_H);
    u.h[4] = __float2bfloat16(b[0] * SCALE_H);
    u.h[5] = __float2bfloat16(b[1] * SCALE_H);
    u.h[6] = __float2bfloat16(b[2] * SCALE_H);
    u.h[7] = __float2bfloat16(b[3] * SCALE_H);
    ((s8v*)hb)[t] = u.v;
}

// ---- kernel 2: pos2[i] = 2*log2e * dot_f32(h_i[i], h_j[i]) ----
__global__ void pos_kernel(const float* __restrict__ hi, const float* __restrict__ hj,
                           float* __restrict__ pos2) {
    int w = threadIdx.x >> 6, l = threadIdx.x & 63;
    int row = blockIdx.x * 4 + w;
    f2v a = ((const f2v*)(hi + (size_t)row * DD))[l];
    f2v b = ((const f2v*)(hj + (size_t)row * DD))[l];
    float d = a[0] * b[0] + a[1] * b[1];
    #pragma unroll
    for (int off = 32; off; off >>= 1) d += __shfl_xor(d, off, 64);
    if (l == 0) pos2[row] = SCALE2 * d;
}

// ---- kernel 3: fused sim*S2 + masked online logsumexp (log2 domain) ----
// Block: 256 thr = 4 waves. Wave (wm,wn). Rows: {r0..r0+15} U {+B} (fm picks half).
// Cols per step: {pc0..pc0+31} U {+B} (fn&1 picks 16-col subtile, fn>>1 picks +B half).
// One S load feeds 4 sim elements (fm x colhalf).
__global__ __launch_bounds__(256, 3)
void main_kernel(const __hip_bfloat16* __restrict__ hb, const float* __restrict__ S,
                 float* __restrict__ msplit, float* __restrict__ ssplit) {
    const int tid = threadIdx.x;
    const int l  = tid & 63;
    const int w  = tid >> 6;
    const int wm = w >> 1, wn = w & 1;
    const int rb = blockIdx.x & 127;
    const int cs = blockIdx.x >> 7;
    const int r0 = rb * 32 + wm * 16;    // wave row base (first half)
    const int c0 = cs * 512;             // pair-column range for this split
    const int lc = l & 15;               // frag row/col within 16
    const int lk = l >> 4;               // k-group

    const s8v* hb8 = (const s8v*)hb;     // 16 x s8v per row of 128 bf16

    // A fragments, hoisted for the entire sweep: afr[fm][kk]
    s8v afr[2][4];
    #pragma unroll
    for (int fm = 0; fm < 2; fm++) {
        int ar = r0 + lc + fm * B_ROWS;
        #pragma unroll
        for (int kk = 0; kk < 4; kk++)
            afr[fm][kk] = hb8[ar * 16 + kk * 4 + lk];
    }

    float m[2][4], ssum[2][4];
    #pragma unroll
    for (int fm = 0; fm < 2; fm++)
        #pragma unroll
        for (int r = 0; r < 4; r++) { m[fm][r] = MINIT; ssum[fm][r] = 0.f; }

    const int srowbase = r0 + lk * 4;    // S row (== gr & 4095) for (r)

    for (int t = 0; t < 8; t++) {
        const int pc0 = c0 + t * 64 + wn * 32;

        f4v acc[2][4];
        #pragma unroll
        for (int fm = 0; fm < 2; fm++)
            #pragma unroll
            for (int fn = 0; fn < 4; fn++) acc[fm][fn] = f4v{0.f, 0.f, 0.f, 0.f};

        #pragma unroll
        for (int kk = 0; kk < 4; kk++) {
            s8v bfr[4];
            #pragma unroll
            for (int fn = 0; fn < 4; fn++) {
                int bc = pc0 + (fn & 1) * 16 + lc + ((fn >> 1) ? B_ROWS : 0);
                bfr[fn] = hb8[bc * 16 + kk * 4 + lk];
            }
            #pragma unroll
            for (int fm = 0; fm < 2; fm++)
                #pragma unroll
                for (int fn = 0; fn < 4; fn++)
                    acc[fm][fn] = __builtin_amdgcn_mfma_f32_16x16x32_bf16(
                        afr[fm][kk], bfr[fn], acc[fm][fn], 0, 0, 0);
        }

        // epilogue: scale by (1 - S^2), mask, online lse update
        #pragma unroll
        for (int r = 0; r < 4; r++) {
            const int srow = srowbase + r;
            const float* Srow = S + (size_t)srow * B_ROWS;
            #pragma unroll
            for (int fp = 0; fp < 2; fp++) {           // column subtile (fn&1)
                const int scol = pc0 + fp * 16 + lc;
                const float Sv = Srow[scol];
                const float s2 = 1.f - Sv * Sv;
                const bool msk = (scol == srow);       // covers j==n and j==(n+B)%N
                #pragma unroll
                for (int fm = 0; fm < 2; fm++) {
                    #pragma unroll
                    for (int fh = 0; fh < 2; fh++) {   // column +B half (fn>>1)
                        const int fn = fh * 2 + fp;
                        float v1 = msk ? MASKVAL : acc[fm][fn][r] * s2;
                        float nm = fmaxf(m[fm][r], v1);
                        if (nm > m[fm][r]) {           // rare rescale path
                            ssum[fm][r] *= exp2f(m[fm][r] - nm);
                            m[fm][r] = nm;
                        }
                        ssum[fm][r] += exp2f(v1 - nm);
                    }
                }
            }
        }
    }

    // reduce (m,s) across the 16 lanes holding the same row, write per-split state
    #pragma unroll
    for (int fm = 0; fm < 2; fm++) {
        #pragma unroll
        for (int r = 0; r < 4; r++) {
            float mm = m[fm][r], ss = ssum[fm][r];
            #pragma unroll
            for (int off = 1; off < 16; off <<= 1) {
                float mo = __shfl_xor(mm, off, 64);
                float so = __shfl_xor(ss, off, 64);
                float nm = fmaxf(mm, mo);
                ss = ss * exp2f(mm - nm) + so * exp2f(mo - nm);
                mm = nm;
            }
            if (lc == 0) {
                int gr = srowbase + r + fm * B_ROWS;
                int sp = cs * 2 + wn;
                msplit[sp * NN + gr] = mm;
                ssplit[sp * NN + gr] = ss;
            }
        }
    }
}

// ---- kernel 4a: per-row split merge + lse, block partial sums (parallel) ----
// 32 blocks x 256 threads: one thread per row n.
__global__ __launch_bounds__(256)
void reduce_kernel(const float* __restrict__ msplit, const float* __restrict__ ssplit,
                   const float* __restrict__ pos2, float* __restrict__ partial) {
    __shared__ float red[256];
    const int n = blockIdx.x * 256 + threadIdx.x;   // n < 8192
    float p = pos2[n & (B_ROWS - 1)];
    float M = p, Ssum = 1.f;                        // pos logit seeds the lse
    #pragma unroll
    for (int sp = 0; sp < NSPLIT; sp++) {
        float mo = msplit[sp * NN + n];
        float so = ssplit[sp * NN + n];
        float nm = fmaxf(M, mo);
        Ssum = Ssum * exp2f(M - nm) + so * exp2f(mo - nm);
        M = nm;
    }
    red[threadIdx.x] = (M + log2f(Ssum)) - p;       // log2 units
    __syncthreads();
    for (int st = 128; st; st >>= 1) {
        if (threadIdx.x < st) red[threadIdx.x] += red[threadIdx.x + st];
        __syncthreads();
    }
    if (threadIdx.x == 0) partial[blockIdx.x] = red[0];
}

// ---- kernel 4b: deterministic final sum over 32 partials ----
__global__ void final_kernel(const float* __restrict__ partial, float* __restrict__ out) {
    if (threadIdx.x == 0) {
        float s = 0.f;
        #pragma unroll
        for (int i = 0; i < 32; i++) s += partial[i];
        out[0] = s * (LN2 / (float)NN);
    }
}

extern "C" void kernel_launch(void* const* d_in, const int* in_sizes, int n_in,
                              void* d_out, int out_size, void* d_ws, size_t ws_size,
                              hipStream_t stream) {
    (void)in_sizes; (void)n_in; (void)out_size; (void)ws_size;
    const float* hi = (const float*)d_in[0];
    const float* hj = (const float*)d_in[1];
    const float* S  = (const float*)d_in[2];

    char* ws = (char*)d_ws;
    __hip_bfloat16* hb = (__hip_bfloat16*)ws;                      // 2 MB
    float* pos2   = (float*)(ws + 2097152);                        // 16 KB
    float* msplit = (float*)(ws + 2097152 + 16384);                // 512 KB
    float* ssplit = (float*)(ws + 2097152 + 16384 + 524288);       // 512 KB
    float* partial= (float*)(ws + 2097152 + 16384 + 2 * 524288);   // 128 B

    prep_kernel<<<512, 256, 0, stream>>>(hi, hj, hb);
    pos_kernel<<<1024, 256, 0, stream>>>(hi, hj, pos2);
    main_kernel<<<1024, 256, 0, stream>>>(hb, S, msplit, ssplit);
    reduce_kernel<<<32, 256, 0, stream>>>(msplit, ssplit, pos2, partial);
    final_kernel<<<1, 64, 0, stream>>>(partial, (float*)d_out);
}